// Round 3
// baseline (342.210 us; speedup 1.0000x reference)
//
#include <hip/hip_runtime.h>

// LSTM RNN: B=2048, L=256 (257 steps), F=64, H=32, K=2.
// R3: single-wave workgroups — NO inter-wave barriers in the recurrence.
// 1024 wgs x 64 threads; each wave owns 2 batch rows (M dup period-2).
// Per step: 32 MFMA (16 N-tiles x 2 k-frags, Wh in VGPRs) + 2 logit MFMAs.
// h round-trips 256B of LDS within the wave (in-order DS pipe).
// setup_kernel pre-folds weights into d_ws (Wh^T bf16 frag-layout, W_g2@Wi,
// one-hot/bias folds, logit diff column).

typedef __attribute__((ext_vector_type(8))) short bf16x8;
typedef __attribute__((ext_vector_type(4))) float f32x4;

#define L2E 1.44269504088896340736f
#define LN2 0.69314718055994530942f

__device__ __forceinline__ short f2bf(float x) {
    unsigned u = __builtin_bit_cast(unsigned, x);
    unsigned r = (u + 0x7FFFu + ((u >> 16) & 1u)) >> 16;
    return (short)r;
}
__device__ __forceinline__ float fsig(float x) {
    float e = __builtin_amdgcn_exp2f(-L2E * x);
    return __builtin_amdgcn_rcpf(1.0f + e);
}
__device__ __forceinline__ float ftanh(float x) {
    float e = __builtin_amdgcn_exp2f(-2.0f * L2E * x);
    return 2.0f * __builtin_amdgcn_rcpf(1.0f + e) - 1.0f;
}

// ws byte offsets
#define WS_WHT   0          // bf16 [n=256][k=256]  (131072 B)
#define WS_B2T   131072     // bf16 [n=256][k=32]   (16384 B)
#define WS_AMPD  147456     // bf16 [64]            (128 B)
#define WS_C0V   147584     // f32  [256]
#define WS_DSV   148608     // f32  [256]
#define WS_BDF   149632     // f32  [1]

__global__ __launch_bounds__(256) void setup_kernel(
    const float* __restrict__ W_emb, const float* __restrict__ b_emb,
    const float* __restrict__ W_g2, const float* __restrict__ b_g2,
    const float* __restrict__ Wi, const float* __restrict__ Wh,
    const float* __restrict__ b_lstm, const float* __restrict__ W_amp,
    const float* __restrict__ b_amp, unsigned char* __restrict__ ws)
{
    short* whT  = (short*)(ws + WS_WHT);
    short* b2T  = (short*)(ws + WS_B2T);
    short* ampd = (short*)(ws + WS_AMPD);
    float* c0v  = (float*)(ws + WS_C0V);
    float* dsv  = (float*)(ws + WS_DSV);
    float* bdf  = (float*)(ws + WS_BDF);

    const int n = threadIdx.x;   // 256 gate cols
    float acc[35];
    #pragma unroll
    for (int i = 0; i < 35; ++i) acc[i] = 0.f;
    for (int f = 0; f < 64; ++f) {
        float wi = Wi[f * 256 + n];
        #pragma unroll
        for (int k = 0; k < 32; ++k) acc[k] += W_g2[k * 64 + f] * wi;  // uniform loads
        acc[32] += W_emb[f] * wi;
        acc[33] += W_emb[64 + f] * wi;
        acc[34] += (b_emb[f] + b_g2[f]) * wi;
    }
    acc[34] += b_lstm[n];
    #pragma unroll
    for (int k = 0; k < 32; ++k) b2T[n * 32 + k] = f2bf(acc[k]);
    c0v[n] = acc[32] + acc[34];          // s=0 one-hot + const
    dsv[n] = acc[33] - acc[32];          // swap delta for s=1
    for (int k = 0; k < 256; ++k) whT[n * 256 + k] = f2bf(Wh[k * 256 + n]);
    if (n < 64) ampd[n] = f2bf(W_amp[n * 2 + 1] - W_amp[n * 2]);
    if (n == 0) bdf[0] = b_amp[1] - b_amp[0];
}

__global__ __launch_bounds__(64, 1) void lstm_kernel(
    const int* __restrict__ s, const float* __restrict__ g,
    const float* __restrict__ W_g1, const float* __restrict__ b_g1,
    const float* __restrict__ W_gh, const float* __restrict__ b_gh,
    const float* __restrict__ W_gc, const float* __restrict__ b_gc,
    const unsigned char* __restrict__ ws, float* __restrict__ out)
{
    const short* whT  = (const short*)(ws + WS_WHT);
    const short* b2T  = (const short*)(ws + WS_B2T);
    const short* ampd = (const short*)(ws + WS_AMPD);
    const float* c0v  = (const float*)(ws + WS_C0V);
    const float* dsv  = (const float*)(ws + WS_DSV);
    const float* bdf  = (const float*)(ws + WS_BDF);

    __shared__ __align__(16) short Hb[2][128];    // [buf][b(2) * 64 + f(64)] bf16
    __shared__ unsigned char sp_l[257];           // bit b of sp_l[t] = s_pad[b][t]

    const int l   = threadIdx.x;   // 64
    const int n2  = l & 15;        // MFMA col / A-row
    const int q   = l >> 4;        // MFMA quad
    const int wgb = blockIdx.x * 2;
    const int fown = 16 * q + n2;  // owned f for gate phase

    // token staging: sp_l[t] = bits of s[:, t-1]; sp_l[0] = 0
    for (int t = l; t < 257; t += 64) {
        unsigned v = 0;
        if (t >= 1)
            v = (unsigned)(s[(wgb + 0) * 256 + t - 1] & 1) |
                ((unsigned)(s[(wgb + 1) * 256 + t - 1] & 1) << 1);
        sp_l[t] = (unsigned char)v;
    }

    // ---------- static fragments (all registers) ----------
    bf16x8 Bf[16][2];
    #pragma unroll
    for (int tb = 0; tb < 16; ++tb) {
        const int n = tb * 16 + n2;
        #pragma unroll
        for (int kf = 0; kf < 2; ++kf)
            Bf[tb][kf] = *(const bf16x8*)(whT + n * 256 + kf * 32 + q * 8);
    }
    // Atv: tanh head, A-layout (m dup period 2 -> b = n2&1)
    bf16x8 Atv;
    {
        const float g_a = g[wgb + (n2 & 1)];
        #pragma unroll
        for (int j = 0; j < 8; ++j) {
            int k = q * 8 + j;
            Atv[j] = f2bf(tanhf(g_a * W_g1[k] + b_g1[k]));
        }
    }
    // C0[tile] = Atv @ B2 + (one-hot s=0 + const) fold
    f32x4 C0[16];
    {
        const f32x4 zero4 = {0.f, 0.f, 0.f, 0.f};
        #pragma unroll
        for (int tb = 0; tb < 16; ++tb) {
            bf16x8 b2f = *(const bf16x8*)(b2T + (tb * 16 + n2) * 32 + q * 8);
            C0[tb] = __builtin_amdgcn_mfma_f32_16x16x32_bf16(Atv, b2f, zero4, 0, 0, 0);
            float ca = c0v[tb * 16 + n2];
            #pragma unroll
            for (int r = 0; r < 4; ++r) C0[tb][r] += ca;
        }
    }
    // logit diff column (col 0 only)
    bf16x8 BLd0 = {0,0,0,0,0,0,0,0}, BLd1 = {0,0,0,0,0,0,0,0};
    f32x4 CL0 = {0.f, 0.f, 0.f, 0.f};
    if (n2 == 0) {
        BLd0 = *(const bf16x8*)(ampd + q * 8);
        BLd1 = *(const bf16x8*)(ampd + 32 + q * 8);
        float bd = bdf[0];
        CL0[0] = bd; CL0[1] = bd; CL0[2] = bd; CL0[3] = bd;
    }
    // per-lane s-delta for the 4 gates at owned f
    float Dsel4[4];
    #pragma unroll
    for (int gi = 0; gi < 4; ++gi) Dsel4[gi] = dsv[gi * 64 + fown];

    // state init: c0/h0
    float cst[2];
    #pragma unroll
    for (int b = 0; b < 2; ++b) {
        float gb = g[wgb + b];
        cst[b] = gb * W_gc[fown] + b_gc[fown];
        Hb[0][b * 64 + fown] = f2bf(gb * W_gh[fown] + b_gh[fown]);
    }
    __syncthreads();

    // ---------- recurrence: 257 steps, single wave, no inter-wave sync ----------
    const bool mq1 = (q & 1) != 0, mq2 = (q & 2) != 0;
    const int raddr = (n2 & 1) * 64 + q * 8;     // shorts
    float slp0 = 0.f, slp1 = 0.f;

    for (int t = 0; t <= 256; ++t) {
        const int rb = t & 1;
        const short* rbuf = &Hb[rb][0];
        bf16x8 a0 = *(const bf16x8*)(rbuf + raddr);        // f 0..31
        bf16x8 a1 = *(const bf16x8*)(rbuf + raddr + 32);   // f 32..63
        const unsigned spt = sp_l[t];

        f32x4 acc[16];
        #pragma unroll
        for (int tb = 0; tb < 16; ++tb) {
            f32x4 tmp = __builtin_amdgcn_mfma_f32_16x16x32_bf16(a1, Bf[tb][1], C0[tb], 0, 0, 0);
            acc[tb]   = __builtin_amdgcn_mfma_f32_16x16x32_bf16(a0, Bf[tb][0], tmp, 0, 0, 0);
        }
        f32x4 tL  = __builtin_amdgcn_mfma_f32_16x16x32_bf16(a1, BLd1, CL0, 0, 0, 0);
        f32x4 accL = __builtin_amdgcn_mfma_f32_16x16x32_bf16(a0, BLd0, tL, 0, 0, 0);

        const float fr0 = (float)(spt & 1u);
        const float fr1 = (float)((spt >> 1) & 1u);

        if (t >= 1) {   // log-prob of token s[:,t-1] under logits from h_t
            #pragma unroll
            for (int r = 0; r < 2; ++r) {
                float d = accL[r];                       // l1 - l0 for b=r
                float x = ((spt >> r) & 1u) ? -d : d;    // l_other - l_s
                float e = __builtin_amdgcn_exp2f(L2E * x);
                float sp = LN2 * __builtin_amdgcn_logf(1.0f + e);  // v_log = log2
                if (r == 0) slp0 -= sp; else slp1 -= sp;
            }
        }

        if (t < 256) {
            // extract z for owned (b, f=16q+n2): tile 4g+q, reg b
            float z[4][2];
            #pragma unroll
            for (int gi = 0; gi < 4; ++gi) {
                #pragma unroll
                for (int b = 0; b < 2; ++b) {
                    float x01 = mq1 ? acc[4 * gi + 1][b] : acc[4 * gi + 0][b];
                    float x23 = mq1 ? acc[4 * gi + 3][b] : acc[4 * gi + 2][b];
                    float fr  = b ? fr1 : fr0;
                    z[gi][b] = (mq2 ? x23 : x01) + fr * Dsel4[gi];
                }
            }
            short* wbuf = &Hb[1 - rb][0];
            #pragma unroll
            for (int b = 0; b < 2; ++b) {
                float si = fsig(z[0][b]), sf = fsig(z[1][b]);
                float tg = ftanh(z[2][b]), so = fsig(z[3][b]);
                float c = sf * cst[b] + si * tg;
                cst[b] = c;
                float h = so * ftanh(c);
                wbuf[b * 64 + fown] = f2bf(h);
            }
        }
        __syncthreads();   // single-wave: cheap; orders LDS + blocks compiler reordering
    }

    if (l == 0) {
        out[wgb + 0] = slp0;
        out[wgb + 1] = slp1;
    }
}

extern "C" void kernel_launch(void* const* d_in, const int* in_sizes, int n_in,
                              void* d_out, int out_size, void* d_ws, size_t ws_size,
                              hipStream_t stream) {
    (void)in_sizes; (void)n_in; (void)out_size; (void)ws_size;
    const int*   s      = (const int*)d_in[0];
    const float* g      = (const float*)d_in[1];
    const float* W_emb  = (const float*)d_in[2];
    const float* b_emb  = (const float*)d_in[3];
    const float* W_g1   = (const float*)d_in[4];
    const float* b_g1   = (const float*)d_in[5];
    const float* W_g2   = (const float*)d_in[6];
    const float* b_g2   = (const float*)d_in[7];
    const float* W_gh   = (const float*)d_in[8];
    const float* b_gh   = (const float*)d_in[9];
    const float* W_gc   = (const float*)d_in[10];
    const float* b_gc   = (const float*)d_in[11];
    const float* Wi     = (const float*)d_in[12];
    const float* Wh     = (const float*)d_in[13];
    const float* b_lstm = (const float*)d_in[14];
    const float* W_amp  = (const float*)d_in[15];
    const float* b_amp  = (const float*)d_in[16];
    float* out = (float*)d_out;
    unsigned char* ws = (unsigned char*)d_ws;

    setup_kernel<<<1, 256, 0, stream>>>(W_emb, b_emb, W_g2, b_g2, Wi, Wh,
                                        b_lstm, W_amp, b_amp, ws);
    lstm_kernel<<<1024, 64, 0, stream>>>(s, g, W_g1, b_g1, W_gh, b_gh,
                                         W_gc, b_gc, ws, out);
}

// Round 4
// 300.447 us; speedup vs baseline: 1.1390x; 1.1390x over previous
//
#include <hip/hip_runtime.h>

// LSTM RNN: B=2048, L=256 (257 steps), F=64, H=32, K=2.
// R4: single-wave wgs, ZERO barriers / ZERO LDS round-trips in the loop.
// 1024 wgs x 64 threads, 2 batch rows/wave (M dup period-2).
// h exchange via ds_bpermute (lane l owns packed {h0[f=l],h1[f=l]} dword);
// 16 bpermute + 8 v_perm rebuild A-frags each step. Token byte prefetched.
// Per step: 32 gate MFMAs + 2 logit MFMAs + 2 C0-fold (preamble only).
// setup_kernel pre-folds weights into d_ws (Wh^T bf16 frag-layout, W_g2@Wi,
// one-hot/bias folds, logit diff column).

typedef __attribute__((ext_vector_type(8))) short bf16x8;
typedef __attribute__((ext_vector_type(4))) float f32x4;
typedef __attribute__((ext_vector_type(4))) unsigned u32x4;

#define L2E 1.44269504088896340736f
#define LN2 0.69314718055994530942f

__device__ __forceinline__ short f2bf(float x) {
    unsigned u = __builtin_bit_cast(unsigned, x);
    unsigned r = (u + 0x7FFFu + ((u >> 16) & 1u)) >> 16;
    return (short)r;
}
__device__ __forceinline__ float fsig(float x) {
    float e = __builtin_amdgcn_exp2f(-L2E * x);
    return __builtin_amdgcn_rcpf(1.0f + e);
}
__device__ __forceinline__ float ftanh(float x) {
    float e = __builtin_amdgcn_exp2f(-2.0f * L2E * x);
    return 2.0f * __builtin_amdgcn_rcpf(1.0f + e) - 1.0f;
}

// ws byte offsets
#define WS_WHT   0          // bf16 [n=256][k=256]  (131072 B)
#define WS_B2T   131072     // bf16 [n=256][k=32]   (16384 B)
#define WS_AMPD  147456     // bf16 [64]            (128 B)
#define WS_C0V   147584     // f32  [256]
#define WS_DSV   148608     // f32  [256]
#define WS_BDF   149632     // f32  [1]

__global__ __launch_bounds__(256) void setup_kernel(
    const float* __restrict__ W_emb, const float* __restrict__ b_emb,
    const float* __restrict__ W_g2, const float* __restrict__ b_g2,
    const float* __restrict__ Wi, const float* __restrict__ Wh,
    const float* __restrict__ b_lstm, const float* __restrict__ W_amp,
    const float* __restrict__ b_amp, unsigned char* __restrict__ ws)
{
    short* whT  = (short*)(ws + WS_WHT);
    short* b2T  = (short*)(ws + WS_B2T);
    short* ampd = (short*)(ws + WS_AMPD);
    float* c0v  = (float*)(ws + WS_C0V);
    float* dsv  = (float*)(ws + WS_DSV);
    float* bdf  = (float*)(ws + WS_BDF);

    const int n = threadIdx.x;   // 256 gate cols
    float acc[35];
    #pragma unroll
    for (int i = 0; i < 35; ++i) acc[i] = 0.f;
    for (int f = 0; f < 64; ++f) {
        float wi = Wi[f * 256 + n];
        #pragma unroll
        for (int k = 0; k < 32; ++k) acc[k] += W_g2[k * 64 + f] * wi;  // uniform loads
        acc[32] += W_emb[f] * wi;
        acc[33] += W_emb[64 + f] * wi;
        acc[34] += (b_emb[f] + b_g2[f]) * wi;
    }
    acc[34] += b_lstm[n];
    #pragma unroll
    for (int k = 0; k < 32; ++k) b2T[n * 32 + k] = f2bf(acc[k]);
    c0v[n] = acc[32] + acc[34];          // s=0 one-hot + const
    dsv[n] = acc[33] - acc[32];          // swap delta for s=1
    for (int k = 0; k < 256; ++k) whT[n * 256 + k] = f2bf(Wh[k * 256 + n]);
    if (n < 64) ampd[n] = f2bf(W_amp[n * 2 + 1] - W_amp[n * 2]);
    if (n == 0) bdf[0] = b_amp[1] - b_amp[0];
}

__global__ __launch_bounds__(64, 1) void lstm_kernel(
    const int* __restrict__ s, const float* __restrict__ g,
    const float* __restrict__ W_g1, const float* __restrict__ b_g1,
    const float* __restrict__ W_gh, const float* __restrict__ b_gh,
    const float* __restrict__ W_gc, const float* __restrict__ b_gc,
    const unsigned char* __restrict__ ws, float* __restrict__ out)
{
    const short* whT  = (const short*)(ws + WS_WHT);
    const short* b2T  = (const short*)(ws + WS_B2T);
    const short* ampd = (const short*)(ws + WS_AMPD);
    const float* c0v  = (const float*)(ws + WS_C0V);
    const float* dsv  = (const float*)(ws + WS_DSV);
    const float* bdf  = (const float*)(ws + WS_BDF);

    __shared__ unsigned char sp_l[260];   // bit b of sp_l[t] = s_pad[b][t]

    const int l   = threadIdx.x;   // 64
    const int n2  = l & 15;        // MFMA col / A-row
    const int q   = l >> 4;        // MFMA quad
    const int wgb = blockIdx.x * 2;
    // gate-phase: lane l owns f = l for BOTH batch rows

    // token staging: sp_l[t] = bits of s[:, t-1]; sp_l[0] = 0; pad 257..259 = 0
    for (int t = l; t < 260; t += 64) {
        unsigned v = 0;
        if (t >= 1 && t <= 256)
            v = (unsigned)(s[(wgb + 0) * 256 + t - 1] & 1) |
                ((unsigned)(s[(wgb + 1) * 256 + t - 1] & 1) << 1);
        sp_l[t] = (unsigned char)v;
    }

    // ---------- static fragments (all registers) ----------
    bf16x8 Bf[16][2];
    #pragma unroll
    for (int tb = 0; tb < 16; ++tb) {
        const int n = tb * 16 + n2;
        #pragma unroll
        for (int kf = 0; kf < 2; ++kf)
            Bf[tb][kf] = *(const bf16x8*)(whT + n * 256 + kf * 32 + q * 8);
    }
    // Atv: tanh head, A-layout (m dup period 2 -> b = n2&1)
    bf16x8 Atv;
    {
        const float g_a = g[wgb + (n2 & 1)];
        #pragma unroll
        for (int j = 0; j < 8; ++j) {
            int k = q * 8 + j;
            Atv[j] = f2bf(tanhf(g_a * W_g1[k] + b_g1[k]));
        }
    }
    // C0[tile] = Atv @ B2 + (one-hot s=0 + const) fold
    f32x4 C0[16];
    {
        const f32x4 zero4 = {0.f, 0.f, 0.f, 0.f};
        #pragma unroll
        for (int tb = 0; tb < 16; ++tb) {
            bf16x8 b2f = *(const bf16x8*)(b2T + (tb * 16 + n2) * 32 + q * 8);
            C0[tb] = __builtin_amdgcn_mfma_f32_16x16x32_bf16(Atv, b2f, zero4, 0, 0, 0);
            float ca = c0v[tb * 16 + n2];
            #pragma unroll
            for (int r = 0; r < 4; ++r) C0[tb][r] += ca;
        }
    }
    // logit diff column (col 0 only)
    bf16x8 BLd0 = {0,0,0,0,0,0,0,0}, BLd1 = {0,0,0,0,0,0,0,0};
    f32x4 CL0 = {0.f, 0.f, 0.f, 0.f};
    if (n2 == 0) {
        BLd0 = *(const bf16x8*)(ampd + q * 8);
        BLd1 = *(const bf16x8*)(ampd + 32 + q * 8);
        float bd = bdf[0];
        CL0[0] = bd; CL0[1] = bd; CL0[2] = bd; CL0[3] = bd;
    }
    // per-lane s-delta for the 4 gates at owned f = l
    float Dsel4[4];
    #pragma unroll
    for (int gi = 0; gi < 4; ++gi) Dsel4[gi] = dsv[gi * 64 + l];

    // state init: c0/h0; hw = packed {bf16 h0[b=0], bf16 h0[b=1]} at f = l
    float cst[2];
    int hw;
    {
        float g0 = g[wgb + 0], g1 = g[wgb + 1];
        cst[0] = g0 * W_gc[l] + b_gc[l];
        cst[1] = g1 * W_gc[l] + b_gc[l];
        unsigned h0 = (unsigned short)f2bf(g0 * W_gh[l] + b_gh[l]);
        unsigned h1 = (unsigned short)f2bf(g1 * W_gh[l] + b_gh[l]);
        hw = (int)(h0 | (h1 << 16));
    }
    __syncthreads();   // ONE barrier total (sp_l visibility); none in the loop

    // ---------- recurrence: 257 steps, single wave, barrier-free ----------
    const bool mq1 = (q & 1) != 0, mq2 = (q & 2) != 0;
    const int baseA = q * 32;                               // byte addr of lane q*8
    const unsigned selv = (n2 & 1) ? 0x07060302u : 0x05040100u;
    float slp0 = 0.f, slp1 = 0.f;
    unsigned spt = 0;                                       // sp_l[0]

    for (int t = 0; t <= 256; ++t) {
        unsigned spt_n = sp_l[t + 1];      // prefetch, consumed next iter

        // A-frag rebuild from hw via single-stage bpermute crossbar
        int pA[8], pB[8];
        #pragma unroll
        for (int j = 0; j < 8; ++j) {
            pA[j] = __builtin_amdgcn_ds_bpermute(baseA + 4 * j, hw);
            pB[j] = __builtin_amdgcn_ds_bpermute(baseA + 128 + 4 * j, hw);
        }
        u32x4 a0u, a1u;
        #pragma unroll
        for (int d = 0; d < 4; ++d) {
            a0u[d] = __builtin_amdgcn_perm((unsigned)pA[2 * d + 1], (unsigned)pA[2 * d], selv);
            a1u[d] = __builtin_amdgcn_perm((unsigned)pB[2 * d + 1], (unsigned)pB[2 * d], selv);
        }
        bf16x8 a0 = __builtin_bit_cast(bf16x8, a0u);
        bf16x8 a1 = __builtin_bit_cast(bf16x8, a1u);

        f32x4 acc[16];
        #pragma unroll
        for (int tb = 0; tb < 16; ++tb) {
            f32x4 tmp = __builtin_amdgcn_mfma_f32_16x16x32_bf16(a1, Bf[tb][1], C0[tb], 0, 0, 0);
            acc[tb]   = __builtin_amdgcn_mfma_f32_16x16x32_bf16(a0, Bf[tb][0], tmp, 0, 0, 0);
        }
        f32x4 tL   = __builtin_amdgcn_mfma_f32_16x16x32_bf16(a1, BLd1, CL0, 0, 0, 0);
        f32x4 accL = __builtin_amdgcn_mfma_f32_16x16x32_bf16(a0, BLd0, tL, 0, 0, 0);

        const float fr0 = (float)(spt & 1u);
        const float fr1 = (float)((spt >> 1) & 1u);

        if (t >= 1) {   // log-prob of token s[:,t-1] under logits from h_t
            #pragma unroll
            for (int r = 0; r < 2; ++r) {
                float d = accL[r];                       // l1 - l0 for b=r (lane 0)
                float x = ((spt >> r) & 1u) ? -d : d;    // l_other - l_s
                float e = __builtin_amdgcn_exp2f(L2E * x);
                float sp = LN2 * __builtin_amdgcn_logf(1.0f + e);
                if (r == 0) slp0 -= sp; else slp1 -= sp;
            }
        }

        if (t < 256) {
            // z for owned (b, f=l): tile 4gi+q, reg r=b
            float z[4][2];
            #pragma unroll
            for (int gi = 0; gi < 4; ++gi) {
                #pragma unroll
                for (int b = 0; b < 2; ++b) {
                    float x01 = mq1 ? acc[4 * gi + 1][b] : acc[4 * gi + 0][b];
                    float x23 = mq1 ? acc[4 * gi + 3][b] : acc[4 * gi + 2][b];
                    float fr  = b ? fr1 : fr0;
                    z[gi][b] = (mq2 ? x23 : x01) + fr * Dsel4[gi];
                }
            }
            unsigned hparts[2];
            #pragma unroll
            for (int b = 0; b < 2; ++b) {
                float si = fsig(z[0][b]), sf = fsig(z[1][b]);
                float tg = ftanh(z[2][b]), so = fsig(z[3][b]);
                float c = sf * cst[b] + si * tg;
                cst[b] = c;
                hparts[b] = (unsigned short)f2bf(so * ftanh(c));
            }
            hw = (int)(hparts[0] | (hparts[1] << 16));
        }
        spt = spt_n;
    }

    if (l == 0) {
        out[wgb + 0] = slp0;
        out[wgb + 1] = slp1;
    }
}

extern "C" void kernel_launch(void* const* d_in, const int* in_sizes, int n_in,
                              void* d_out, int out_size, void* d_ws, size_t ws_size,
                              hipStream_t stream) {
    (void)in_sizes; (void)n_in; (void)out_size; (void)ws_size;
    const int*   s      = (const int*)d_in[0];
    const float* g      = (const float*)d_in[1];
    const float* W_emb  = (const float*)d_in[2];
    const float* b_emb  = (const float*)d_in[3];
    const float* W_g1   = (const float*)d_in[4];
    const float* b_g1   = (const float*)d_in[5];
    const float* W_g2   = (const float*)d_in[6];
    const float* b_g2   = (const float*)d_in[7];
    const float* W_gh   = (const float*)d_in[8];
    const float* b_gh   = (const float*)d_in[9];
    const float* W_gc   = (const float*)d_in[10];
    const float* b_gc   = (const float*)d_in[11];
    const float* Wi     = (const float*)d_in[12];
    const float* Wh     = (const float*)d_in[13];
    const float* b_lstm = (const float*)d_in[14];
    const float* W_amp  = (const float*)d_in[15];
    const float* b_amp  = (const float*)d_in[16];
    float* out = (float*)d_out;
    unsigned char* ws = (unsigned char*)d_ws;

    setup_kernel<<<1, 256, 0, stream>>>(W_emb, b_emb, W_g2, b_g2, Wi, Wh,
                                        b_lstm, W_amp, b_amp, ws);
    lstm_kernel<<<1024, 64, 0, stream>>>(s, g, W_g1, b_g1, W_gh, b_gh,
                                         W_gc, b_gc, ws, out);
}